// Round 13
// baseline (581.254 us; speedup 1.0000x reference)
//
#include <hip/hip_runtime.h>
#include <hip/hip_bf16.h>
#include <stdint.h>

#define VOCAB 30000
#define EMBED 256
#define HID   128
#define BB    256
#define TT    512
#define G4    512        // gate columns per direction
#define GWH   1024       // f16 columns in EW2 ([dir][u][g] packed)
#define BPB   16         // batches per lstm block (full MFMA M-dim)

typedef _Float16 f16x8 __attribute__((ext_vector_type(8)));
typedef _Float16 f16x4 __attribute__((ext_vector_type(4)));
typedef float    f32x4 __attribute__((ext_vector_type(4)));

// gate scales folded into EW and U at build time:
//   i,f,o : z' = -log2(e)  * z   -> sigm = rcp(1 + exp2(z'))
//   g     : z' = +2log2(e) * z   -> tanh = 1 - 2*rcp(1 + exp2(z'))
#define S_IFO (-1.4426950408889634f)
#define S_G   ( 2.8853900817779268f)

__device__ __forceinline__ float fexp2(float x){
#if __has_builtin(__builtin_amdgcn_exp2f)
  return __builtin_amdgcn_exp2f(x);
#else
  return exp2f(x);
#endif
}
__device__ __forceinline__ float frcp(float x){
#if __has_builtin(__builtin_amdgcn_rcpf)
  return __builtin_amdgcn_rcpf(x);
#else
  return 1.0f/x;
#endif
}
__device__ __forceinline__ float sigm_p(float zp){ return frcp(1.0f + fexp2(zp)); }
__device__ __forceinline__ float tanh_p(float zp){ return 1.0f - 2.0f*frcp(1.0f + fexp2(zp)); }
__device__ __forceinline__ float tanh_rt(float x){ return 1.0f - 2.0f*frcp(1.0f + fexp2(S_G*x)); }

// ---------------------------------------------------------------------------
// Kernel 1: EW2[v][dirc*512 + u*4 + g] = f16( gsc[g] * (emb[v]@Wcol + b) )
// ---------------------------------------------------------------------------
__global__ __launch_bounds__(256, 4) void embw_mfma(
    const float* __restrict__ emb,
    const float* __restrict__ Wf, const float* __restrict__ Wb,
    const float* __restrict__ bf, const float* __restrict__ bb,
    _Float16* __restrict__ EW)
{
  __shared__ _Float16 As[64*EMBED];   // 32 KB
  const int tid  = threadIdx.x;
  const int l    = tid & 63;
  const int w    = tid >> 6;
  const int r0   = blockIdx.x * 64;
  const int dirc = blockIdx.y >> 3;
  const int u0   = (blockIdx.y & 7) * 16;
  const int nr   = min(64, VOCAB - r0);

  const float4* asrc = (const float4*)(emb + (size_t)r0*EMBED);
  for (int i = tid; i < nr*(EMBED/4); i += 256){
    float4 v = asrc[i];
    const int row = i >> 6;
    const int kc  = (i & 63) * 4;
    const int ks  = kc ^ ((row & 7) << 3);
    _Float16* dst = &As[row*EMBED + ks];
    dst[0]=(_Float16)v.x; dst[1]=(_Float16)v.y;
    dst[2]=(_Float16)v.z; dst[3]=(_Float16)v.w;
  }
  __syncthreads();

  const int cl = w*16 + (l & 15);
  const int ul = cl >> 2;             // 0..15
  const int g  = cl & 3;              // gate
  const int cg = g*128 + u0 + ul;     // original column in [0,512)
  const float* Wsrc = (dirc ? Wb : Wf) + cg;
  const int kg = (l >> 4) * 8;

  f32x4 acc[4] = {{0,0,0,0},{0,0,0,0},{0,0,0,0},{0,0,0,0}};

  for (int kk = 0; kk < EMBED/32; ++kk){
    const int kb = kk*32 + kg;
    f16x8 bfrag;
    #pragma unroll
    for (int j = 0; j < 8; ++j)
      bfrag[j] = (_Float16)Wsrc[(size_t)(kb + j)*G4];
    #pragma unroll
    for (int m = 0; m < 4; ++m){
      const int row = m*16 + (l & 15);
      const int ks  = kb ^ ((row & 7) << 3);
      f16x8 afrag = *(const f16x8*)&As[row*EMBED + ks];
      acc[m] = __builtin_amdgcn_mfma_f32_16x16x32_f16(afrag, bfrag, acc[m], 0, 0, 0);
    }
  }

  const float bv  = (dirc ? bb : bf)[cg];
  const float gsc = (g == 2) ? S_G : S_IFO;
  const int   co  = dirc*512 + (u0 + ul)*4 + g;    // f16 col in EW2
  #pragma unroll
  for (int m = 0; m < 4; ++m){
    #pragma unroll
    for (int r = 0; r < 4; ++r){
      const int vrow = r0 + m*16 + (l >> 4)*4 + r;
      if (vrow < VOCAB)
        EW[(size_t)vrow*GWH + co] = (_Float16)((acc[m][r] + bv) * gsc);
    }
  }
}

// ---------------------------------------------------------------------------
// Kernel 2: recurrence, 16 batches x 1 dir per block (grid 32, 1 block/CU:
// 128 MFMA/CU/step = 620cyc floor, ALL 16 D-rows real). Wave w owns ucols
// [w*16,w*16+16) x 4 gates; U resident 64 VGPR. xw is the MFMA C-IN (f16x4
// per batch, cvt'd off-path; 2-step-deep named A/B pipeline). h in XOR-
// swizzled dbuf LDS (r7-verified). Gates on all 64 lanes (4 units each,
// pre-scaled exp2/rcp). ONE barrier/step.
// ---------------------------------------------------------------------------
__global__ __launch_bounds__(512, 2) void lstm_b16(
    const int*      __restrict__ tokens,
    const _Float16* __restrict__ EW,
    const float*    __restrict__ Ufw, const float* __restrict__ Ubw,
    float* __restrict__ out)
{
  __shared__ _Float16 h_lds[2][16*HID];   // 2 x 4 KB, XOR-swizzled 16B chunks
  __shared__ int      tok_lds[BPB*TT];    // 32 KB

  const int tid = threadIdx.x;
  const int l   = tid & 63;
  const int w   = tid >> 6;               // wave 0..7
  const int lr  = l & 15;
  const int hi  = l >> 4;
  const int dir = blockIdx.x & 1;
  const int b0  = (blockIdx.x >> 1) * BPB;

  for (int i = tid; i < 2*16*HID; i += 512) ((_Float16*)h_lds)[i] = (_Float16)0.f;
  for (int i = tid; i < BPB*TT; i += 512)
    tok_lds[i] = tokens[(b0 + (i >> 9))*TT + (i & 511)];
  __syncthreads();

  // ---- resident U B-fragments (pre-scaled): ub[kt][gate], 64 VGPRs ----
  // B[k][n]: lane col n = lr -> ucol = w*16+lr ; k = kt*32 + hi*8 + j
  const float* U = dir ? Ubw : Ufw;
  f16x8 ub[4][4];
  #pragma unroll
  for (int kt = 0; kt < 4; ++kt){
    #pragma unroll
    for (int g = 0; g < 4; ++g){
      const int   col = g*128 + w*16 + lr;
      const float gs  = (g == 2) ? S_G : S_IFO;
      f16x8 f;
      #pragma unroll
      for (int j = 0; j < 8; ++j)
        f[j] = (_Float16)(U[(size_t)(kt*32 + hi*8 + j)*G4 + col] * gs);
      ub[kt][g] = f;
    }
  }

  const int u = w*16 + lr;               // this lane's hidden unit
  f32x4 creg = {0.f,0.f,0.f,0.f};
  float hfin[4] = {0.f,0.f,0.f,0.f};
  const _Float16* ebase = EW + dir*512 + u*4;
  float* outp[4];
  #pragma unroll
  for (int r = 0; r < 4; ++r)
    outp[r] = out + (size_t)(b0 + hi*4 + r)*TT*(2*HID) + (size_t)dir*HID + u;

  #define TIDX(S) ({ int ss_ = (S); ss_ = ss_ < TT ? ss_ : TT-1;             \
                     dir ? (TT-1-ss_) : ss_; })

  // ---- prologue: xw loads for steps 0/1; addresses for 2/3 ----
  f16x4 ldA[4], ldB[4];
  const _Float16 *adA[4], *adB[4];
  {
    const int t0 = TIDX(0), t1 = TIDX(1), t2 = TIDX(2), t3 = TIDX(3);
    #pragma unroll
    for (int r = 0; r < 4; ++r){
      ldA[r] = *(const f16x4*)(ebase + (size_t)tok_lds[(hi*4+r)*TT + t0]*GWH);
      ldB[r] = *(const f16x4*)(ebase + (size_t)tok_lds[(hi*4+r)*TT + t1]*GWH);
      adA[r] = ebase + (size_t)tok_lds[(hi*4+r)*TT + t2]*GWH;
      adB[r] = ebase + (size_t)tok_lds[(hi*4+r)*TT + t3]*GWH;
    }
  }

  #define STEP(LD, AD, SCUR, CUR)                                            \
  {                                                                          \
    const int t_ = dir ? (TT-1-(SCUR)) : (SCUR);                             \
    /* A-frags (swizzled) + tokens for step SCUR+4 (early lgkm issue) */     \
    f16x8 ha[4];                                                             \
    _Pragma("unroll")                                                        \
    for (int kt = 0; kt < 4; ++kt){                                          \
      const int chunk = (kt*4 + hi) ^ (lr & 7);                              \
      ha[kt] = *(const f16x8*)&h_lds[CUR][lr*HID + chunk*8];                 \
    }                                                                        \
    int tk4[4];                                                              \
    { const int t4 = TIDX((SCUR)+4);                                         \
      _Pragma("unroll")                                                      \
      for (int r = 0; r < 4; ++r) tk4[r] = tok_lds[(hi*4+r)*TT + t4]; }      \
    /* C-in from the 2-step-old loads */                                     \
    f32x4 cin[4];                                                            \
    _Pragma("unroll")                                                        \
    for (int g = 0; g < 4; ++g){                                             \
      _Pragma("unroll")                                                      \
      for (int r = 0; r < 4; ++r) cin[g][r] = (float)LD[r][g];               \
    }                                                                        \
    /* reload pipeline: LD <- mem[AD] (for SCUR+2), AD <- addr(SCUR+4) */    \
    _Pragma("unroll")                                                        \
    for (int r = 0; r < 4; ++r){                                             \
      LD[r] = *(const f16x4*)AD[r];                                          \
      AD[r] = ebase + (size_t)tk4[r]*GWH;                                    \
    }                                                                        \
    /* MFMA: acc[g][r] = z[batch hi*4+r][gate g, unit u] */                  \
    f32x4 acc[4];                                                            \
    _Pragma("unroll")                                                        \
    for (int g = 0; g < 4; ++g)                                              \
      acc[g] = __builtin_amdgcn_mfma_f32_16x16x32_f16(ha[0], ub[0][g], cin[g], 0,0,0); \
    _Pragma("unroll")                                                        \
    for (int kt = 1; kt < 4; ++kt){                                          \
      _Pragma("unroll")                                                      \
      for (int g = 0; g < 4; ++g)                                            \
        acc[g] = __builtin_amdgcn_mfma_f32_16x16x32_f16(ha[kt], ub[kt][g], acc[g], 0,0,0); \
    }                                                                        \
    /* gates: all 64 lanes, 4 (batch,unit) pairs each */                     \
    _Pragma("unroll")                                                        \
    for (int r = 0; r < 4; ++r){                                             \
      const float si = sigm_p(acc[0][r]);                                    \
      const float sf = sigm_p(acc[1][r]);                                    \
      const float tg = tanh_p(acc[2][r]);                                    \
      const float so = sigm_p(acc[3][r]);                                    \
      const float cn = sf*creg[r] + si*tg;                                   \
      creg[r] = cn;                                                          \
      const float hh = so*tanh_rt(cn);                                       \
      hfin[r] = hh;                                                          \
      const int row  = hi*4 + r;                                             \
      const int fidx = row*HID + ((((u >> 3) ^ (row & 7)) & 15) << 3) + (u & 7); \
      h_lds[(CUR)^1][fidx] = (_Float16)hh;                                   \
      outp[r][(size_t)t_*(2*HID)] = hh;                                      \
    }                                                                        \
    asm volatile("s_waitcnt lgkmcnt(0)" ::: "memory");                       \
    __builtin_amdgcn_s_barrier();                                            \
  }

  for (int s = 0; s < TT; s += 2){
    STEP(ldA, adA, s,     0)
    STEP(ldB, adB, s + 1, 1)
  }
  #undef STEP
  #undef TIDX

  // ---- final h_T / c_T ----
  {
    const size_t O1 = (size_t)BB*TT*(2*HID);
    #pragma unroll
    for (int r = 0; r < 4; ++r){
      const size_t idx = (size_t)(b0 + hi*4 + r)*HID + u;
      if (dir == 0){
        out[O1                    + idx] = hfin[r];
        out[O1 +   (size_t)BB*HID + idx] = creg[r];
      } else {
        out[O1 + 2*(size_t)BB*HID + idx] = hfin[r];
        out[O1 + 3*(size_t)BB*HID + idx] = creg[r];
      }
    }
  }
}

extern "C" void kernel_launch(void* const* d_in, const int* in_sizes, int n_in,
                              void* d_out, int out_size, void* d_ws, size_t ws_size,
                              hipStream_t stream)
{
  const int*   tokens = (const int*)  d_in[0];
  const float* emb    = (const float*)d_in[1];
  const float* Wf     = (const float*)d_in[2];
  const float* Ufw    = (const float*)d_in[3];
  const float* bf     = (const float*)d_in[4];
  const float* Wb     = (const float*)d_in[5];
  const float* Ubw    = (const float*)d_in[6];
  const float* bb     = (const float*)d_in[7];
  float* out = (float*)d_out;
  _Float16* EW = (_Float16*)d_ws;     // 30000 x 1024 f16 = 61.44 MB

  embw_mfma<<<dim3((VOCAB + 63)/64, 16), 256, 0, stream>>>(emb, Wf, Wb, bf, bb, EW);
  lstm_b16<<<(BB/BPB)*2, 512, 0, stream>>>(tokens, EW, Ufw, Ubw, out);
}

// Round 14
// 443.606 us; speedup vs baseline: 1.3103x; 1.3103x over previous
//
#include <hip/hip_runtime.h>
#include <hip/hip_bf16.h>
#include <stdint.h>

#define VOCAB 30000
#define EMBED 256
#define HID   128
#define BB    256
#define TT    512
#define G4    512        // gate columns per direction
#define GWH   1024       // f16 columns in EW2 ([dir][u][g] packed)

typedef _Float16 f16x8 __attribute__((ext_vector_type(8)));
typedef _Float16 f16x4 __attribute__((ext_vector_type(4)));
typedef float    f32x4 __attribute__((ext_vector_type(4)));

// gate scales folded into EW and U at build time:
//   i,f,o : z' = -log2(e)  * z   -> sigm = rcp(1 + exp2(z'))
//   g     : z' = +2log2(e) * z   -> tanh = 1 - 2*rcp(1 + exp2(z'))
#define S_IFO (-1.4426950408889634f)
#define S_G   ( 2.8853900817779268f)

__device__ __forceinline__ float fexp2(float x){
#if __has_builtin(__builtin_amdgcn_exp2f)
  return __builtin_amdgcn_exp2f(x);
#else
  return exp2f(x);
#endif
}
__device__ __forceinline__ float frcp(float x){
#if __has_builtin(__builtin_amdgcn_rcpf)
  return __builtin_amdgcn_rcpf(x);
#else
  return 1.0f/x;
#endif
}
__device__ __forceinline__ float sigm_p(float zp){ return frcp(1.0f + fexp2(zp)); }
__device__ __forceinline__ float tanh_p(float zp){ return 1.0f - 2.0f*frcp(1.0f + fexp2(zp)); }
__device__ __forceinline__ float tanh_rt(float x){ return 1.0f - 2.0f*frcp(1.0f + fexp2(S_G*x)); }

// ---------------------------------------------------------------------------
// Kernel 1: EW2[v][dirc*512 + u*4 + g] = f16( gsc[g] * (emb[v]@Wcol + b) )
// Grid (469, 2): y = dir only. Each block stages its 64-row emb tile ONCE
// and loops the 8 u-groups (W slices are L2-resident) -> emb HBM reads drop
// from 16x to 2x of the table (491 MB -> 61 MB).
// ---------------------------------------------------------------------------
__global__ __launch_bounds__(256, 4) void embw_mfma(
    const float* __restrict__ emb,
    const float* __restrict__ Wf, const float* __restrict__ Wb,
    const float* __restrict__ bf, const float* __restrict__ bb,
    _Float16* __restrict__ EW)
{
  __shared__ _Float16 As[64*EMBED];   // 32 KB
  const int tid  = threadIdx.x;
  const int l    = tid & 63;
  const int w    = tid >> 6;
  const int r0   = blockIdx.x * 64;
  const int dirc = blockIdx.y;
  const int nr   = min(64, VOCAB - r0);

  const float4* asrc = (const float4*)(emb + (size_t)r0*EMBED);
  for (int i = tid; i < nr*(EMBED/4); i += 256){
    float4 v = asrc[i];
    const int row = i >> 6;
    const int kc  = (i & 63) * 4;
    const int ks  = kc ^ ((row & 7) << 3);
    _Float16* dst = &As[row*EMBED + ks];
    dst[0]=(_Float16)v.x; dst[1]=(_Float16)v.y;
    dst[2]=(_Float16)v.z; dst[3]=(_Float16)v.w;
  }
  __syncthreads();

  const int cl = w*16 + (l & 15);
  const int ul = cl >> 2;             // 0..15 within u-group
  const int g  = cl & 3;              // gate
  const int kg = (l >> 4) * 8;
  const float* Wbase = dirc ? Wb : Wf;
  const float* bbase = dirc ? bb : bf;
  const float gsc = (g == 2) ? S_G : S_IFO;

  for (int u0 = 0; u0 < HID; u0 += 16){
    const int cg = g*128 + u0 + ul;   // original column in [0,512)
    const float* Wsrc = Wbase + cg;

    f32x4 acc[4] = {{0,0,0,0},{0,0,0,0},{0,0,0,0},{0,0,0,0}};

    for (int kk = 0; kk < EMBED/32; ++kk){
      const int kb = kk*32 + kg;
      f16x8 bfrag;
      #pragma unroll
      for (int j = 0; j < 8; ++j)
        bfrag[j] = (_Float16)Wsrc[(size_t)(kb + j)*G4];
      #pragma unroll
      for (int m = 0; m < 4; ++m){
        const int row = m*16 + (l & 15);
        const int ks  = kb ^ ((row & 7) << 3);
        f16x8 afrag = *(const f16x8*)&As[row*EMBED + ks];
        acc[m] = __builtin_amdgcn_mfma_f32_16x16x32_f16(afrag, bfrag, acc[m], 0, 0, 0);
      }
    }

    const float bv = bbase[cg];
    const int   co = dirc*512 + (u0 + ul)*4 + g;   // f16 col in EW2
    #pragma unroll
    for (int m = 0; m < 4; ++m){
      #pragma unroll
      for (int r = 0; r < 4; ++r){
        const int vrow = r0 + m*16 + (l >> 4)*4 + r;
        if (vrow < VOCAB)
          EW[(size_t)vrow*GWH + co] = (_Float16)((acc[m][r] + bv) * gsc);
      }
    }
  }
}

// ---------------------------------------------------------------------------
// Kernel 2: recurrence — r10 structure verbatim (measured floor of this
// decomposition: 128 MFMA/CU/step = 620cyc and VALU 518cyc both minimal at
// P=2). Persistent accumulators, pre-scaled activations, LDS tokens,
// 2-step-deep xw pipeline, ONE barrier/step. Block = 2 batches x 1 dir.
// ---------------------------------------------------------------------------
__global__ __launch_bounds__(512, 2) void lstm_r10(
    const int*      __restrict__ tokens,
    const _Float16* __restrict__ EW,
    const float*    __restrict__ Ufw, const float* __restrict__ Ubw,
    float* __restrict__ out)
{
  __shared__ _Float16 h_lds[2][320];   // batch0 @ f16 idx 0, batch1 @ 160 (pad)
  __shared__ int      tok_lds[2*TT];   // 4 KB

  const int tid = threadIdx.x;
  const int l   = tid & 63;
  const int w   = tid >> 6;               // wave 0..7
  const int lr  = l & 15;
  const int hi  = l >> 4;
  const int dir = blockIdx.x & 1;
  const int b0  = (blockIdx.x >> 1) * 2;

  if (tid < 640) ((_Float16*)h_lds)[tid] = (_Float16)0.f;
  for (int i = tid; i < 2*TT; i += 512)
    tok_lds[i] = tokens[(b0 + (i >> 9))*TT + (i & 511)];
  __syncthreads();

  // ---- resident U B-fragments (pre-scaled): ub[kt][gate], 64 VGPRs ----
  const float* U = dir ? Ubw : Ufw;
  f16x8 ub[4][4];
  #pragma unroll
  for (int kt = 0; kt < 4; ++kt){
    #pragma unroll
    for (int g = 0; g < 4; ++g){
      const int   col = g*128 + w*16 + lr;
      const float gs  = (g == 2) ? S_G : S_IFO;
      f16x8 f;
      #pragma unroll
      for (int j = 0; j < 8; ++j)
        f[j] = (_Float16)(U[(size_t)(kt*32 + hi*8 + j)*G4 + col] * gs);
      ub[kt][g] = f;
    }
  }

  const int  bsel = (l >> 2) & 1;      // A-row -> batch
  const bool act  = (l < 32);
  const int  q    = hi & 1;            // batch (lanes 0-31); 32-63 mirror
  const int  u    = w*16 + lr;         // hidden unit

  float creg = 0.f, hfin = 0.f;
  const _Float16* ebase = EW + dir*512 + u*4;

  // persistent accumulators: rows 1-3 accumulate garbage, never read
  f32x4 aP[4];
  #pragma unroll
  for (int g = 0; g < 4; ++g) aP[g] = (f32x4){0.f,0.f,0.f,0.f};

  #define AADDR(S) ({ int ss_ = (S); ss_ = ss_ < TT ? ss_ : TT-1;            \
                      const int tt_ = dir ? (TT-1-ss_) : ss_;                \
                      ebase + (size_t)tok_lds[q*TT + tt_]*GWH; })

  f16x4 xwA = *(const f16x4*)AADDR(0);
  f16x4 xwB = *(const f16x4*)AADDR(1);
  const _Float16* adA = AADDR(2);
  const _Float16* adB = AADDR(3);

  #define STEP(XW, AD, SCUR, CUR)                                            \
  {                                                                          \
    const int t_ = dir ? (TT-1-(SCUR)) : (SCUR);                             \
    f16x8 ha[4];                                                             \
    _Pragma("unroll")                                                        \
    for (int kt = 0; kt < 4; ++kt)                                           \
      ha[kt] = *(const f16x8*)&h_lds[CUR][bsel*160 + kt*32 + hi*8];          \
    _Pragma("unroll")                                                        \
    for (int g = 0; g < 4; ++g) aP[g][0] = (float)XW[g];                     \
    XW = *(const f16x4*)AD;            /* reload this slot for SCUR+2 */     \
    AD = AADDR((SCUR)+4);              /* address for the next reload */     \
    _Pragma("unroll")                                                        \
    for (int kt = 0; kt < 4; ++kt){                                          \
      _Pragma("unroll")                                                      \
      for (int g = 0; g < 4; ++g)                                            \
        aP[g] = __builtin_amdgcn_mfma_f32_16x16x32_f16(ha[kt], ub[kt][g], aP[g], 0,0,0); \
    }                                                                        \
    if (act){                                                                \
      const float si = sigm_p(aP[0][0]);                                     \
      const float sf = sigm_p(aP[1][0]);                                     \
      const float tg = tanh_p(aP[2][0]);                                     \
      const float so = sigm_p(aP[3][0]);                                     \
      const float cn = sf*creg + si*tg;                                      \
      creg = cn;                                                             \
      const float hh = so*tanh_rt(cn);                                       \
      hfin = hh;                                                             \
      h_lds[(CUR)^1][q*160 + u] = (_Float16)hh;                              \
      out[((size_t)(b0+q)*TT + t_)*(2*HID) + (size_t)dir*HID + u] = hh;      \
    }                                                                        \
    asm volatile("s_waitcnt lgkmcnt(0)" ::: "memory");                       \
    __builtin_amdgcn_s_barrier();                                            \
  }

  for (int s = 0; s < TT; s += 2){
    STEP(xwA, adA, s,     0)
    STEP(xwB, adB, s + 1, 1)
  }
  #undef STEP
  #undef AADDR

  // ---- final h_T / c_T ----
  if (act){
    const size_t O1  = (size_t)BB*TT*(2*HID);
    const size_t idx = (size_t)(b0+q)*HID + u;
    if (dir == 0){
      out[O1                    + idx] = hfin;
      out[O1 +   (size_t)BB*HID + idx] = creg;
    } else {
      out[O1 + 2*(size_t)BB*HID + idx] = hfin;
      out[O1 + 3*(size_t)BB*HID + idx] = creg;
    }
  }
}

extern "C" void kernel_launch(void* const* d_in, const int* in_sizes, int n_in,
                              void* d_out, int out_size, void* d_ws, size_t ws_size,
                              hipStream_t stream)
{
  const int*   tokens = (const int*)  d_in[0];
  const float* emb    = (const float*)d_in[1];
  const float* Wf     = (const float*)d_in[2];
  const float* Ufw    = (const float*)d_in[3];
  const float* bf     = (const float*)d_in[4];
  const float* Wb     = (const float*)d_in[5];
  const float* Ubw    = (const float*)d_in[6];
  const float* bb     = (const float*)d_in[7];
  float* out = (float*)d_out;
  _Float16* EW = (_Float16*)d_ws;     // 30000 x 1024 f16 = 61.44 MB

  embw_mfma<<<dim3((VOCAB + 63)/64, 2), 256, 0, stream>>>(emb, Wf, Wb, bf, bb, EW);
  lstm_r10<<<BB, 512, 0, stream>>>(tokens, EW, Ufw, Ubw, out);
}

// Round 15
// 353.317 us; speedup vs baseline: 1.6451x; 1.2555x over previous
//
#include <hip/hip_runtime.h>
#include <hip/hip_bf16.h>
#include <stdint.h>

#define VOCAB 30000
#define EMBED 256
#define HID   128
#define BB    256
#define TT    512
#define G4    512        // gate columns per direction
#define GWH   1024       // f16 columns in EW2 ([dir][u][g] packed)
#define BPB   4          // batches per lstm block (D-rows 0,4,8,12)
#define HSTR  160        // f16 stride per batch row in h_lds (320 B)

typedef _Float16 f16x8 __attribute__((ext_vector_type(8)));
typedef _Float16 f16x4 __attribute__((ext_vector_type(4)));
typedef float    f32x4 __attribute__((ext_vector_type(4)));

// gate scales folded into EW and U at build time:
//   i,f,o : z' = -log2(e)  * z   -> sigm = rcp(1 + exp2(z'))
//   g     : z' = +2log2(e) * z   -> tanh = 1 - 2*rcp(1 + exp2(z'))
#define S_IFO (-1.4426950408889634f)
#define S_G   ( 2.8853900817779268f)

__device__ __forceinline__ float fexp2(float x){
#if __has_builtin(__builtin_amdgcn_exp2f)
  return __builtin_amdgcn_exp2f(x);
#else
  return exp2f(x);
#endif
}
__device__ __forceinline__ float frcp(float x){
#if __has_builtin(__builtin_amdgcn_rcpf)
  return __builtin_amdgcn_rcpf(x);
#else
  return 1.0f/x;
#endif
}
__device__ __forceinline__ float sigm_p(float zp){ return frcp(1.0f + fexp2(zp)); }
__device__ __forceinline__ float tanh_p(float zp){ return 1.0f - 2.0f*frcp(1.0f + fexp2(zp)); }
__device__ __forceinline__ float tanh_rt(float x){ return 1.0f - 2.0f*frcp(1.0f + fexp2(S_G*x)); }

// ---------------------------------------------------------------------------
// Kernel 1: EW2[v][dirc*512 + u*4 + g] = f16( gsc[g] * (emb[v]@Wcol + b) )
// r10 config (grid 469x16): emb re-reads are L3-absorbed; measured ~90 us.
// ---------------------------------------------------------------------------
__global__ __launch_bounds__(256, 4) void embw_mfma(
    const float* __restrict__ emb,
    const float* __restrict__ Wf, const float* __restrict__ Wb,
    const float* __restrict__ bf, const float* __restrict__ bb,
    _Float16* __restrict__ EW)
{
  __shared__ _Float16 As[64*EMBED];   // 32 KB
  const int tid  = threadIdx.x;
  const int l    = tid & 63;
  const int w    = tid >> 6;
  const int r0   = blockIdx.x * 64;
  const int dirc = blockIdx.y >> 3;
  const int u0   = (blockIdx.y & 7) * 16;
  const int nr   = min(64, VOCAB - r0);

  const float4* asrc = (const float4*)(emb + (size_t)r0*EMBED);
  for (int i = tid; i < nr*(EMBED/4); i += 256){
    float4 v = asrc[i];
    const int row = i >> 6;
    const int kc  = (i & 63) * 4;
    const int ks  = kc ^ ((row & 7) << 3);
    _Float16* dst = &As[row*EMBED + ks];
    dst[0]=(_Float16)v.x; dst[1]=(_Float16)v.y;
    dst[2]=(_Float16)v.z; dst[3]=(_Float16)v.w;
  }
  __syncthreads();

  const int cl = w*16 + (l & 15);
  const int ul = cl >> 2;             // 0..15
  const int g  = cl & 3;              // gate
  const int cg = g*128 + u0 + ul;     // original column in [0,512)
  const float* Wsrc = (dirc ? Wb : Wf) + cg;
  const int kg = (l >> 4) * 8;

  f32x4 acc[4] = {{0,0,0,0},{0,0,0,0},{0,0,0,0},{0,0,0,0}};

  for (int kk = 0; kk < EMBED/32; ++kk){
    const int kb = kk*32 + kg;
    f16x8 bfrag;
    #pragma unroll
    for (int j = 0; j < 8; ++j)
      bfrag[j] = (_Float16)Wsrc[(size_t)(kb + j)*G4];
    #pragma unroll
    for (int m = 0; m < 4; ++m){
      const int row = m*16 + (l & 15);
      const int ks  = kb ^ ((row & 7) << 3);
      f16x8 afrag = *(const f16x8*)&As[row*EMBED + ks];
      acc[m] = __builtin_amdgcn_mfma_f32_16x16x32_f16(afrag, bfrag, acc[m], 0, 0, 0);
    }
  }

  const float bv  = (dirc ? bb : bf)[cg];
  const float gsc = (g == 2) ? S_G : S_IFO;
  const int   co  = dirc*512 + (u0 + ul)*4 + g;    // f16 col in EW2
  #pragma unroll
  for (int m = 0; m < 4; ++m){
    #pragma unroll
    for (int r = 0; r < 4; ++r){
      const int vrow = r0 + m*16 + (l >> 4)*4 + r;
      if (vrow < VOCAB)
        EW[(size_t)vrow*GWH + co] = (_Float16)((acc[m][r] + bv) * gsc);
    }
  }
}

// ---------------------------------------------------------------------------
// Kernel 2: recurrence, BPB=4 (grid 128, ~1 block/CU). Per-CU per-step:
// 128 MFMA (620cyc, half of r10) AND 1 gate-unit/thread on ALL 64 lanes.
// Batches in D-rows 0,4,8,12 -> lane (hi,lr) reg 0 = z[batch hi][unit
// w*16+lr]. A-reads 2-way-conflict-free (batch stride 320B). Persistent
// accs, pre-scaled acts, LDS tokens, 2-step xw pipeline, 1 barrier/step.
// ---------------------------------------------------------------------------
__global__ __launch_bounds__(512, 2) void lstm_b4(
    const int*      __restrict__ tokens,
    const _Float16* __restrict__ EW,
    const float*    __restrict__ Ufw, const float* __restrict__ Ubw,
    float* __restrict__ out)
{
  __shared__ _Float16 h_lds[2][BPB*HSTR];  // 2 x 1.25 KB
  __shared__ int      tok_lds[BPB*TT];     // 8 KB

  const int tid = threadIdx.x;
  const int l   = tid & 63;
  const int w   = tid >> 6;               // wave 0..7
  const int lr  = l & 15;
  const int hi  = l >> 4;
  const int dir = blockIdx.x & 1;
  const int b0  = (blockIdx.x >> 1) * BPB;

  for (int i = tid; i < 2*BPB*HSTR; i += 512) ((_Float16*)h_lds)[i] = (_Float16)0.f;
  for (int i = tid; i < BPB*TT; i += 512)
    tok_lds[i] = tokens[(b0 + (i >> 9))*TT + (i & 511)];
  __syncthreads();

  // ---- resident U B-fragments (pre-scaled): ub[kt][gate], 64 VGPRs ----
  const float* U = dir ? Ubw : Ufw;
  f16x8 ub[4][4];
  #pragma unroll
  for (int kt = 0; kt < 4; ++kt){
    #pragma unroll
    for (int g = 0; g < 4; ++g){
      const int   col = g*128 + w*16 + lr;
      const float gs  = (g == 2) ? S_G : S_IFO;
      f16x8 f;
      #pragma unroll
      for (int j = 0; j < 8; ++j)
        f[j] = (_Float16)(U[(size_t)(kt*32 + hi*8 + j)*G4 + col] * gs);
      ub[kt][g] = f;
    }
  }

  const int bsel = lr >> 2;            // A-row 4j -> batch j (others dup)
  const int q    = hi;                 // gate batch for this lane
  const int u    = w*16 + lr;          // gate hidden unit

  float creg = 0.f, hfin = 0.f;
  const _Float16* ebase = EW + dir*512 + u*4;

  // persistent accumulators: regs 1-3 accumulate garbage, never read
  f32x4 aP[4];
  #pragma unroll
  for (int g = 0; g < 4; ++g) aP[g] = (f32x4){0.f,0.f,0.f,0.f};

  #define AADDR(S) ({ int ss_ = (S); ss_ = ss_ < TT ? ss_ : TT-1;            \
                      const int tt_ = dir ? (TT-1-ss_) : ss_;                \
                      ebase + (size_t)tok_lds[q*TT + tt_]*GWH; })

  f16x4 xwA = *(const f16x4*)AADDR(0);
  f16x4 xwB = *(const f16x4*)AADDR(1);
  const _Float16* adA = AADDR(2);
  const _Float16* adB = AADDR(3);

  #define STEP(XW, AD, SCUR, CUR)                                            \
  {                                                                          \
    const int t_ = dir ? (TT-1-(SCUR)) : (SCUR);                             \
    f16x8 ha[4];                                                             \
    _Pragma("unroll")                                                        \
    for (int kt = 0; kt < 4; ++kt)                                           \
      ha[kt] = *(const f16x8*)&h_lds[CUR][bsel*HSTR + kt*32 + hi*8];         \
    _Pragma("unroll")                                                        \
    for (int g = 0; g < 4; ++g) aP[g][0] = (float)XW[g];                     \
    XW = *(const f16x4*)AD;            /* reload this slot for SCUR+2 */     \
    AD = AADDR((SCUR)+4);              /* address for the next reload */     \
    _Pragma("unroll")                                                        \
    for (int kt = 0; kt < 4; ++kt){                                          \
      _Pragma("unroll")                                                      \
      for (int g = 0; g < 4; ++g)                                            \
        aP[g] = __builtin_amdgcn_mfma_f32_16x16x32_f16(ha[kt], ub[kt][g], aP[g], 0,0,0); \
    }                                                                        \
    {                                                                        \
      const float si = sigm_p(aP[0][0]);                                     \
      const float sf = sigm_p(aP[1][0]);                                     \
      const float tg = tanh_p(aP[2][0]);                                     \
      const float so = sigm_p(aP[3][0]);                                     \
      const float cn = sf*creg + si*tg;                                      \
      creg = cn;                                                             \
      const float hh = so*tanh_rt(cn);                                       \
      hfin = hh;                                                             \
      h_lds[(CUR)^1][q*HSTR + u] = (_Float16)hh;                             \
      out[((size_t)(b0+q)*TT + t_)*(2*HID) + (size_t)dir*HID + u] = hh;      \
    }                                                                        \
    asm volatile("s_waitcnt lgkmcnt(0)" ::: "memory");                       \
    __builtin_amdgcn_s_barrier();                                            \
  }

  for (int s = 0; s < TT; s += 2){
    STEP(xwA, adA, s,     0)
    STEP(xwB, adB, s + 1, 1)
  }
  #undef STEP
  #undef AADDR

  // ---- final h_T / c_T (each thread owns one (batch,unit)) ----
  {
    const size_t O1  = (size_t)BB*TT*(2*HID);
    const size_t idx = (size_t)(b0+q)*HID + u;
    if (dir == 0){
      out[O1                    + idx] = hfin;
      out[O1 +   (size_t)BB*HID + idx] = creg;
    } else {
      out[O1 + 2*(size_t)BB*HID + idx] = hfin;
      out[O1 + 3*(size_t)BB*HID + idx] = creg;
    }
  }
}

extern "C" void kernel_launch(void* const* d_in, const int* in_sizes, int n_in,
                              void* d_out, int out_size, void* d_ws, size_t ws_size,
                              hipStream_t stream)
{
  const int*   tokens = (const int*)  d_in[0];
  const float* emb    = (const float*)d_in[1];
  const float* Wf     = (const float*)d_in[2];
  const float* Ufw    = (const float*)d_in[3];
  const float* bf     = (const float*)d_in[4];
  const float* Wb     = (const float*)d_in[5];
  const float* Ubw    = (const float*)d_in[6];
  const float* bb     = (const float*)d_in[7];
  float* out = (float*)d_out;
  _Float16* EW = (_Float16*)d_ws;     // 30000 x 1024 f16 = 61.44 MB

  embw_mfma<<<dim3((VOCAB + 63)/64, 16), 256, 0, stream>>>(emb, Wf, Wb, bf, bb, EW);
  lstm_b4<<<(BB/BPB)*2, 512, 0, stream>>>(tokens, EW, Ufw, Ubw, out);
}

// Round 16
// 323.826 us; speedup vs baseline: 1.7950x; 1.0911x over previous
//
#include <hip/hip_runtime.h>
#include <hip/hip_bf16.h>
#include <stdint.h>

#define VOCAB 30000
#define EMBED 256
#define HID   128
#define BB    256
#define TT    512
#define G4    512        // gate columns per direction
#define GWH   1024       // f16 columns in EW2 ([dir][u][g] packed)
#define BPB   4          // batches per lstm block (D-rows 0,4,8,12)
#define HSTR  160        // f16 stride per batch row in h_lds (320 B)

typedef _Float16 f16x8 __attribute__((ext_vector_type(8)));
typedef _Float16 f16x4 __attribute__((ext_vector_type(4)));
typedef float    f32x4 __attribute__((ext_vector_type(4)));

// gate scales folded into EW / Wp / U at build time:
//   i,f,o : z' = -log2(e)  * z   -> sigm = rcp(1 + exp2(z'))
//   g     : z' = +2log2(e) * z   -> tanh = 1 - 2*rcp(1 + exp2(z'))
#define S_IFO (-1.4426950408889634f)
#define S_G   ( 2.8853900817779268f)

__device__ __forceinline__ float fexp2(float x){
#if __has_builtin(__builtin_amdgcn_exp2f)
  return __builtin_amdgcn_exp2f(x);
#else
  return exp2f(x);
#endif
}
__device__ __forceinline__ float frcp(float x){
#if __has_builtin(__builtin_amdgcn_rcpf)
  return __builtin_amdgcn_rcpf(x);
#else
  return 1.0f/x;
#endif
}
__device__ __forceinline__ float sigm_p(float zp){ return frcp(1.0f + fexp2(zp)); }
__device__ __forceinline__ float tanh_p(float zp){ return 1.0f - 2.0f*frcp(1.0f + fexp2(zp)); }
__device__ __forceinline__ float tanh_rt(float x){ return 1.0f - 2.0f*frcp(1.0f + fexp2(S_G*x)); }

// ---------------------------------------------------------------------------
// Kernel 0: pack W into B-fragment layout, f16, pre-scaled.
// Wp[dirc][kt][c][hi][j] ; c = u*4+g (packed col), k = kt*32 + hi*8 + j.
// 2*8*512*4*8 = 512K f16 = 1 MB. One f16x8 store per thread-index.
// ---------------------------------------------------------------------------
__global__ __launch_bounds__(256) void wpack(
    const float* __restrict__ Wf, const float* __restrict__ Wb,
    _Float16* __restrict__ Wp)
{
  const int idx  = blockIdx.x*256 + threadIdx.x;   // 32768 = 2*8*512*4
  const int hi   = idx & 3;
  const int c    = (idx >> 2) & 511;
  const int kt   = (idx >> 11) & 7;
  const int dirc = idx >> 14;
  const float* W = dirc ? Wb : Wf;
  const int g = c & 3, u = c >> 2;
  const int cg = g*128 + u;                        // original column
  const float gs = (g == 2) ? S_G : S_IFO;
  f16x8 v;
  #pragma unroll
  for (int j = 0; j < 8; ++j)
    v[j] = (_Float16)(W[(size_t)(kt*32 + hi*8 + j)*G4 + cg] * gs);
  *(f16x8*)&Wp[(size_t)idx*8] = v;
}

// ---------------------------------------------------------------------------
// Kernel 1: EW2[v][dirc*512 + c] = f16( emb[v]@W(c) * gsc + b*gsc )
// B-fragments now ONE f16x8 load each from Wp (was 64 scalar strided loads).
// ---------------------------------------------------------------------------
__global__ __launch_bounds__(256, 4) void embw_mfma(
    const float* __restrict__ emb,
    const _Float16* __restrict__ Wp,
    const float* __restrict__ bf, const float* __restrict__ bb,
    _Float16* __restrict__ EW)
{
  __shared__ _Float16 As[64*EMBED];   // 32 KB
  const int tid  = threadIdx.x;
  const int l    = tid & 63;
  const int w    = tid >> 6;
  const int r0   = blockIdx.x * 64;
  const int dirc = blockIdx.y >> 3;
  const int u0   = (blockIdx.y & 7) * 16;
  const int nr   = min(64, VOCAB - r0);

  const float4* asrc = (const float4*)(emb + (size_t)r0*EMBED);
  for (int i = tid; i < nr*(EMBED/4); i += 256){
    float4 v = asrc[i];
    const int row = i >> 6;
    const int kc  = (i & 63) * 4;
    const int ks  = kc ^ ((row & 7) << 3);
    _Float16* dst = &As[row*EMBED + ks];
    dst[0]=(_Float16)v.x; dst[1]=(_Float16)v.y;
    dst[2]=(_Float16)v.z; dst[3]=(_Float16)v.w;
  }
  __syncthreads();

  const int cl = w*16 + (l & 15);
  const int c  = u0*4 + cl;           // packed col in [0,512)
  const int ul = cl >> 2;
  const int g  = cl & 3;
  const int cg = g*128 + u0 + ul;     // original column
  const int hi = l >> 4;

  f32x4 acc[4] = {{0,0,0,0},{0,0,0,0},{0,0,0,0},{0,0,0,0}};

  for (int kt = 0; kt < 8; ++kt){
    // B fragment: one 16-B load from the packed table
    const f16x8 bfrag = *(const f16x8*)&Wp[((size_t)((dirc*8 + kt)*512 + c)*4 + hi)*8];
    const int kb = kt*32 + hi*8;
    #pragma unroll
    for (int m = 0; m < 4; ++m){
      const int row = m*16 + (l & 15);
      const int ks  = kb ^ ((row & 7) << 3);
      f16x8 afrag = *(const f16x8*)&As[row*EMBED + ks];
      acc[m] = __builtin_amdgcn_mfma_f32_16x16x32_f16(afrag, bfrag, acc[m], 0, 0, 0);
    }
  }

  const float bv  = (dirc ? bb : bf)[cg];
  const float gsc = (g == 2) ? S_G : S_IFO;
  const float bsc = bv * gsc;
  const int   co  = dirc*512 + c;     // f16 col in EW2
  #pragma unroll
  for (int m = 0; m < 4; ++m){
    #pragma unroll
    for (int r = 0; r < 4; ++r){
      const int vrow = r0 + m*16 + (l >> 4)*4 + r;
      if (vrow < VOCAB)
        EW[(size_t)vrow*GWH + co] = (_Float16)(acc[m][r] + bsc);
    }
  }
}

// ---------------------------------------------------------------------------
// Kernel 2: recurrence, BPB=4 (grid 128, ~1 block/CU) — r15 verbatim.
// 128 MFMA/CU/step (620cyc) AND 1 gate-unit/thread on ALL 64 lanes.
// ---------------------------------------------------------------------------
__global__ __launch_bounds__(512, 2) void lstm_b4(
    const int*      __restrict__ tokens,
    const _Float16* __restrict__ EW,
    const float*    __restrict__ Ufw, const float* __restrict__ Ubw,
    float* __restrict__ out)
{
  __shared__ _Float16 h_lds[2][BPB*HSTR];  // 2 x 1.25 KB
  __shared__ int      tok_lds[BPB*TT];     // 8 KB

  const int tid = threadIdx.x;
  const int l   = tid & 63;
  const int w   = tid >> 6;               // wave 0..7
  const int lr  = l & 15;
  const int hi  = l >> 4;
  const int dir = blockIdx.x & 1;
  const int b0  = (blockIdx.x >> 1) * BPB;

  for (int i = tid; i < 2*BPB*HSTR; i += 512) ((_Float16*)h_lds)[i] = (_Float16)0.f;
  for (int i = tid; i < BPB*TT; i += 512)
    tok_lds[i] = tokens[(b0 + (i >> 9))*TT + (i & 511)];
  __syncthreads();

  // ---- resident U B-fragments (pre-scaled): ub[kt][gate], 64 VGPRs ----
  const float* U = dir ? Ubw : Ufw;
  f16x8 ub[4][4];
  #pragma unroll
  for (int kt = 0; kt < 4; ++kt){
    #pragma unroll
    for (int g = 0; g < 4; ++g){
      const int   col = g*128 + w*16 + lr;
      const float gs  = (g == 2) ? S_G : S_IFO;
      f16x8 f;
      #pragma unroll
      for (int j = 0; j < 8; ++j)
        f[j] = (_Float16)(U[(size_t)(kt*32 + hi*8 + j)*G4 + col] * gs);
      ub[kt][g] = f;
    }
  }

  const int bsel = lr >> 2;            // A-row 4j -> batch j (others dup)
  const int q    = hi;                 // gate batch for this lane
  const int u    = w*16 + lr;          // gate hidden unit

  float creg = 0.f, hfin = 0.f;
  const _Float16* ebase = EW + dir*512 + u*4;

  // persistent accumulators: regs 1-3 accumulate garbage, never read
  f32x4 aP[4];
  #pragma unroll
  for (int g = 0; g < 4; ++g) aP[g] = (f32x4){0.f,0.f,0.f,0.f};

  #define AADDR(S) ({ int ss_ = (S); ss_ = ss_ < TT ? ss_ : TT-1;            \
                      const int tt_ = dir ? (TT-1-ss_) : ss_;                \
                      ebase + (size_t)tok_lds[q*TT + tt_]*GWH; })

  f16x4 xwA = *(const f16x4*)AADDR(0);
  f16x4 xwB = *(const f16x4*)AADDR(1);
  const _Float16* adA = AADDR(2);
  const _Float16* adB = AADDR(3);

  #define STEP(XW, AD, SCUR, CUR)                                            \
  {                                                                          \
    const int t_ = dir ? (TT-1-(SCUR)) : (SCUR);                             \
    f16x8 ha[4];                                                             \
    _Pragma("unroll")                                                        \
    for (int kt = 0; kt < 4; ++kt)                                           \
      ha[kt] = *(const f16x8*)&h_lds[CUR][bsel*HSTR + kt*32 + hi*8];         \
    _Pragma("unroll")                                                        \
    for (int g = 0; g < 4; ++g) aP[g][0] = (float)XW[g];                     \
    XW = *(const f16x4*)AD;            /* reload this slot for SCUR+2 */     \
    AD = AADDR((SCUR)+4);              /* address for the next reload */     \
    _Pragma("unroll")                                                        \
    for (int kt = 0; kt < 4; ++kt){                                          \
      _Pragma("unroll")                                                      \
      for (int g = 0; g < 4; ++g)                                            \
        aP[g] = __builtin_amdgcn_mfma_f32_16x16x32_f16(ha[kt], ub[kt][g], aP[g], 0,0,0); \
    }                                                                        \
    {                                                                        \
      const float si = sigm_p(aP[0][0]);                                     \
      const float sf = sigm_p(aP[1][0]);                                     \
      const float tg = tanh_p(aP[2][0]);                                     \
      const float so = sigm_p(aP[3][0]);                                     \
      const float cn = sf*creg + si*tg;                                      \
      creg = cn;                                                             \
      const float hh = so*tanh_rt(cn);                                       \
      hfin = hh;                                                             \
      h_lds[(CUR)^1][q*HSTR + u] = (_Float16)hh;                             \
      out[((size_t)(b0+q)*TT + t_)*(2*HID) + (size_t)dir*HID + u] = hh;      \
    }                                                                        \
    asm volatile("s_waitcnt lgkmcnt(0)" ::: "memory");                       \
    __builtin_amdgcn_s_barrier();                                            \
  }

  for (int s = 0; s < TT; s += 2){
    STEP(xwA, adA, s,     0)
    STEP(xwB, adB, s + 1, 1)
  }
  #undef STEP
  #undef AADDR

  // ---- final h_T / c_T (each thread owns one (batch,unit)) ----
  {
    const size_t O1  = (size_t)BB*TT*(2*HID);
    const size_t idx = (size_t)(b0+q)*HID + u;
    if (dir == 0){
      out[O1                    + idx] = hfin;
      out[O1 +   (size_t)BB*HID + idx] = creg;
    } else {
      out[O1 + 2*(size_t)BB*HID + idx] = hfin;
      out[O1 + 3*(size_t)BB*HID + idx] = creg;
    }
  }
}

extern "C" void kernel_launch(void* const* d_in, const int* in_sizes, int n_in,
                              void* d_out, int out_size, void* d_ws, size_t ws_size,
                              hipStream_t stream)
{
  const int*   tokens = (const int*)  d_in[0];
  const float* emb    = (const float*)d_in[1];
  const float* Wf     = (const float*)d_in[2];
  const float* Ufw    = (const float*)d_in[3];
  const float* bf     = (const float*)d_in[4];
  const float* Wb     = (const float*)d_in[5];
  const float* Ubw    = (const float*)d_in[6];
  const float* bb     = (const float*)d_in[7];
  float* out = (float*)d_out;
  _Float16* EW = (_Float16*)d_ws;                       // 61.44 MB
  _Float16* Wp = (_Float16*)d_ws + (size_t)VOCAB*GWH;   // +1 MB packed W

  wpack<<<128, 256, 0, stream>>>(Wf, Wb, Wp);
  embw_mfma<<<dim3((VOCAB + 63)/64, 16), 256, 0, stream>>>(emb, Wp, bf, bb, EW);
  lstm_b4<<<(BB/BPB)*2, 512, 0, stream>>>(tokens, EW, Ufw, Ubw, out);
}